// Round 12
// baseline (6365.722 us; speedup 1.0000x reference)
//
#include <hip/hip_runtime.h>
#include <cmath>

namespace {
constexpr int Hc = 8, FFc = 512, HIDc = 512;
}

struct Params {
  const float *coords, *Wi, *bi, *W_ph;
  const float *Wq, *Wk, *Wv, *Wo, *g1, *b1, *fW1, *fb1, *fW2, *fb2, *g2, *b2;
  const float *W_node, *W_fixed, *W_step, *W_out, *Wc1, *bc1, *Wc2, *bc2;
  float* out;
};

// Journal R24: R23 post-mortem — the regression was a BUG not a falsified
// theory: runtime-bounded store loops (for i<n) made acc[20] runtime-indexed
// => SCRATCH (rule #20; ka VGPR 52 is the tell, impossible with live acc[20])
// + s_kT stride-20 writes = 8-way conflicts (803K). R24 fixes: (1) static
// #pragma-unroll-20 stores with if(i<n) predication => acc in registers;
// (2) s_kT padded to stride 21 (21 coprime 32; QK^T reads adjusted, layout
// only). QKV/W_node single-read maps retained. kff/out-proj/critic R8 exact.
__device__ __align__(16) float g_bn[120 * 8 * 256]; // BN stats, 8-way replicated
__device__ __align__(16) float g_x[512 * 2560];
__device__ __align__(16) float g_t[512 * 2560];
__device__ __align__(16) float g_crd[512 * 40];
__device__ int   g_idx[512 * 20];
__device__ float g_state[512 * 8];
__device__ __align__(16) float g_ctxq[128];
__device__ __align__(16) float g_cctx[512];
// Interleaved-packed weights: float4 at (k4*J + j) holds W[k4*4+0..3][j]
__device__ __align__(16) float g_Wqp[3 * 16384];    // [l][d4<32][j<128][4]
__device__ __align__(16) float g_Wkp[3 * 16384];
__device__ __align__(16) float g_Wvp[3 * 16384];
__device__ __align__(16) float g_Wop[3 * 16384];    // [l][c4<32][j<128][4]
// FF packs (wave-coherent column split):
__device__ __align__(16) float g_W1q[3 * 65536];    // [l][k4<32][c<4][cg<128][4]: col=cg*4+c
__device__ __align__(16) float g_W2q[3 * 65536];    // [l][k4<128][j<128][4]
__device__ __align__(16) float g_Wnp[49152];        // [e4<32][col<384][4]
__device__ __align__(16) float g_Wfp[16384];        // [e4<32][j<128][4]
__device__ __align__(16) float g_Woup[16384];       // [c4<32][j<128][4]
__device__ __align__(16) float g_Wc1p[65536];       // [e4<32][jj<512][4]

#define DOT4(a, b) ((a).x*(b).x + (a).y*(b).y + (a).z*(b).z + (a).w*(b).w)

__device__ __forceinline__ void bn_coef(int slot, const float* g, const float* bb, float cnt,
                                        float* s_scale, float* s_shift, int tid) {
  if (tid < 128) {
    float sm = 0.f, sq = 0.f;
#pragma unroll
    for (int r = 0; r < 8; r++) {
      const float* s = &g_bn[(slot * 8 + r) * 256];
      sm += s[tid]; sq += s[128 + tid];
    }
    float m_ = sm / cnt;
    float v_ = sq / cnt - m_ * m_;
    float rs = rsqrtf(v_ + 1e-5f);
    float sc = rs * g[tid];
    s_scale[tid] = sc;
    s_shift[tid] = bb[tid] - m_ * sc;
  }
}

__global__ __launch_bounds__(256) void kinit(Params p) {
  const int tid = threadIdx.x, b = blockIdx.x;
  const int gid = b * 256 + tid, GS = 512 * 256;
  for (int i = gid; i < 120 * 8 * 256; i += GS) g_bn[i] = 0.f;
  for (int e = tid; e < 2560; e += 256) {
    int i = e >> 7, d = e & 127;
    float cx = p.coords[b * 40 + 2 * i], cy = p.coords[b * 40 + 2 * i + 1];
    g_x[b * 2560 + e] = cx * p.Wi[d] + cy * p.Wi[128 + d] + p.bi[d];
  }
  if (tid < 40) g_crd[b * 40 + tid] = p.coords[b * 40 + tid];
  if (tid < 20) g_idx[b * 20 + tid] = tid;
  if (tid < 8) g_state[b * 8 + tid] = 0.f;
  if (b == 0) {
    if (tid < 128) {
      float a = 0.f;
      for (int j = 0; j < 256; j++) a += p.W_ph[j] * p.W_step[j * 128 + tid];
      g_ctxq[tid] = a;
    }
    for (int jj = tid; jj < 512; jj += 256) {
      float a = p.bc1[jj];
      for (int e = 0; e < 256; e++) a += p.W_ph[e] * p.Wc1[(128 + e) * 512 + jj];
      g_cctx[jj] = a;
    }
  }
  for (int e = gid; e < 3 * 16384; e += GS) {
    int sub = e & 3, rest = e >> 2;
    int j = rest & 127, rest2 = rest >> 7, d4 = rest2 & 31, l = rest2 >> 5;
    int d = d4 * 4 + sub;
    int src = l * 16384 + (j >> 4) * 2048 + d * 16 + (j & 15);
    g_Wqp[e] = p.Wq[src]; g_Wkp[e] = p.Wk[src]; g_Wvp[e] = p.Wv[src];
    int c = d;
    g_Wop[e] = p.Wo[l * 16384 + (c >> 4) * 2048 + (c & 15) * 128 + j];
  }
  // kff packs (wave-coherent layouts)
  for (int e = gid; e < 3 * 65536; e += GS) {
    int sub = e & 3, f = (e >> 2) & 16383, l = e >> 16;
    int cg = f & 127, c = (f >> 7) & 3, k4 = f >> 9;       // k4<32
    g_W1q[e] = p.fW1[l * 65536 + (k4 * 4 + sub) * 512 + cg * 4 + c];
  }
  for (int e = gid; e < 3 * 65536; e += GS) {
    int sub = e & 3, f = (e >> 2) & 16383, l = e >> 16;
    int j = f & 127, k4 = f >> 7;                          // k4<128
    g_W2q[e] = p.fW2[l * 65536 + (k4 * 4 + sub) * 128 + j];
  }
  for (int e = gid; e < 49152; e += GS) {
    int sub = e & 3, rest = e >> 2;
    int col = rest % 384, e4 = rest / 384;
    g_Wnp[e] = p.W_node[(e4 * 4 + sub) * 384 + col];
  }
  for (int e = gid; e < 16384; e += GS) {
    int sub = e & 3, rest = e >> 2;
    int j = rest & 127, e4 = rest >> 7;
    g_Wfp[e] = p.W_fixed[(e4 * 4 + sub) * 128 + j];
    g_Woup[e] = p.W_out[(e4 * 4 + sub) * 128 + j];
  }
  for (int e = gid; e < 65536; e += GS) {
    int sub = e & 3, rest = e >> 2;
    int jj = rest & 511, e4 = rest >> 9;
    g_Wc1p[e] = p.Wc1[(e4 * 4 + sub) * 512 + jj];
  }
}

// KA (fused ka1+ka2): grid 512, 512 threads, one block per sample.
// QKV: threads 0..383, st=tid>>7 in {q,k,v}, j=tid&127; each thread covers
// ALL n rows => each weight float4 read once per block. Stores statically
// unrolled (acc stays in registers); s_kT stride 21 (conflict-free).
__global__ __launch_bounds__(512, 4) void ka(Params p, int step, int l) {
  const int tid = threadIdx.x, b = blockIdx.x;
  const int n = 20 - step;
  __shared__ __align__(16) float s_t[2560];
  __shared__ __align__(16) float s_q[2560];   // QKV q; reused as AV output h
  __shared__ float s_kT[128 * 21];            // [j<128][i<21] padded
  __shared__ __align__(16) float s_v[2560];
  __shared__ float s_att[3200];               // 8 heads x 400
  __shared__ __align__(16) float s_scale[128], s_shift[128];
  __shared__ float s_bnp[4 * 128 * 2];

  if (l > 0)
    bn_coef(step * 6 + (l - 1) * 2 + 1, p.g2 + (l - 1) * 128, p.b2 + (l - 1) * 128,
            (float)(512 * n), s_scale, s_shift, tid);
  __syncthreads();
  const float4* src4 = (const float4*)((l == 0 ? g_x : g_t) + b * 2560);
  float4* st4 = (float4*)s_t;
  for (int e4 = tid; e4 < n * 32; e4 += 512) {
    float4 x = src4[e4];
    if (l > 0) {
      float4 sc = ((const float4*)s_scale)[e4 & 31];
      float4 sh = ((const float4*)s_shift)[e4 & 31];
      x.x = x.x * sc.x + sh.x; x.y = x.y * sc.y + sh.y;
      x.z = x.z * sc.z + sh.z; x.w = x.w * sc.w + sh.w;
    }
    st4[e4] = x;
  }
  __syncthreads();
  // QKV: threads 0..383. st = tid>>7 (0=q,1=k,2=v), j = tid&127, all n rows.
  if (tid < 384) {
    const int st = tid >> 7, j = tid & 127;
    const float4* w4 = (st == 0 ? (const float4*)g_Wqp
                      : st == 1 ? (const float4*)g_Wkp
                                : (const float4*)g_Wvp) + l * 4096 + j;
    float acc[20];
#pragma unroll
    for (int i = 0; i < 20; i++) acc[i] = 0.f;
    float4 wb0 = w4[0], wb1 = w4[128];
#pragma unroll 2
    for (int d4 = 0; d4 < 32; d4++) {
      float4 wn = w4[((d4 + 2) & 31) * 128];
#pragma unroll
      for (int i = 0; i < 20; i++) {
        if (i < n) acc[i] += DOT4(st4[i * 32 + d4], wb0);
      }
      wb0 = wb1; wb1 = wn;
    }
    // static-index stores (acc stays in registers — rule #20)
    if (st == 0) {
#pragma unroll
      for (int i = 0; i < 20; i++) { if (i < n) s_q[i * 128 + j] = acc[i]; }
    } else if (st == 1) {
#pragma unroll
      for (int i = 0; i < 20; i++) { if (i < n) s_kT[j * 21 + i] = acc[i]; }
    } else {
#pragma unroll
      for (int i = 0; i < 20; i++) { if (i < n) s_v[i * 128 + j] = acc[i]; }
    }
  }
  __syncthreads();
  const int nn = n * n;
  for (int e = tid; e < 8 * nn; e += 512) {
    int hl = e / nn, rem = e % nn, i = rem / n, m = rem % n;
    float dacc = 0.f;
#pragma unroll
    for (int k2 = 0; k2 < 16; k2++)
      dacc += s_q[i * 128 + hl * 16 + k2] * s_kT[(hl * 16 + k2) * 21 + m];
    s_att[hl * 400 + i * 20 + m] = dacc * 0.25f;
  }
  __syncthreads();
  for (int r = tid; r < 8 * n; r += 512) {
    int hl = r / n, i = r % n;
    float* row = s_att + hl * 400 + i * 20;
    float mx = row[0];
    for (int m = 1; m < n; m++) mx = fmaxf(mx, row[m]);
    float s = 0.f;
    for (int m = 0; m < n; m++) { float ev = __expf(row[m] - mx); row[m] = ev; s += ev; }
    float inv = 1.f / s;
    for (int m = 0; m < n; m++) row[m] *= inv;
  }
  __syncthreads();
  // AV -> s_q (s_q free after QK^T)
  for (int e = tid; e < 8 * n * 16; e += 512) {
    int hl = e / (n * 16), rem = e % (n * 16), i = rem >> 4, k2 = rem & 15;
    const float* arow = s_att + hl * 400 + i * 20;
    float acc = 0.f;
    for (int m = 0; m < n; m++) acc += arow[m] * s_v[m * 128 + hl * 16 + k2];
    s_q[i * 128 + hl * 16 + k2] = acc;
  }
  __syncthreads();
  // out-proj + residual -> g_t, BN1 partials. ka2's exact thread->row map.
  {
    const int j2 = tid & 127, rh2 = tid >> 7;
    const int s = rh2 & 1, rhalf = rh2 >> 1;
    const float4* sh4 = (const float4*)s_q;
    float acc[5];
#pragma unroll
    for (int r = 0; r < 5; r++) {
      int i = s + 2 * (rhalf + 2 * r);
      acc[r] = (i < n) ? s_t[i * 128 + j2] : 0.f;
    }
    const float4* wo4 = (const float4*)g_Wop + l * 4096 + j2;
    float4 wb0 = wo4[0], wb1 = wo4[128];
#pragma unroll 2
    for (int c4 = 0; c4 < 32; c4++) {
      float4 wn = wo4[((c4 + 2) & 31) * 128];
#pragma unroll
      for (int r = 0; r < 5; r++) {
        int i = s + 2 * (rhalf + 2 * r);
        if (i < n) { float4 h = sh4[i * 32 + c4]; acc[r] += DOT4(h, wb0); }
      }
      wb0 = wb1; wb1 = wn;
    }
    float sm = 0.f, sq = 0.f;
#pragma unroll
    for (int r = 0; r < 5; r++) {
      int i = s + 2 * (rhalf + 2 * r);
      if (i < n) { g_t[b * 2560 + i * 128 + j2] = acc[r]; sm += acc[r]; sq += acc[r] * acc[r]; }
    }
    s_bnp[(rh2 * 128 + j2) * 2] = sm;
    s_bnp[(rh2 * 128 + j2) * 2 + 1] = sq;
  }
  __syncthreads();
  if (tid < 128) {
    float sm = 0.f, sq = 0.f;
#pragma unroll
    for (int h = 0; h < 4; h++) { sm += s_bnp[(h * 128 + tid) * 2]; sq += s_bnp[(h * 128 + tid) * 2 + 1]; }
    float* slot = &g_bn[((step * 6 + l * 2) * 8 + (b & 7)) * 256];
    atomicAdd(&slot[tid], sm);
    atomicAdd(&slot[128 + tid], sq);
  }
}

// KFF: R19 exact (best measured). grid 32n blocks of 16 rows, 256 threads,
// 2 col-groups x 2 row-waves of 8 rows.
__global__ __launch_bounds__(256, 4) void kff(Params p, int step, int l) {
  const int tid = threadIdx.x, bx = blockIdx.x;
  const int n = 20 - step;
  const int r0 = bx * 16;
  const int wid = tid >> 6, lam = tid & 63;
  const int g = wid >> 1, rh = wid & 1;
  __shared__ __align__(16) float s_x[16 * 128];     // BN1-applied X tile
  __shared__ __align__(16) float s_hid[16 * 512];   // hidden
  __shared__ __align__(16) float s_scale[128], s_shift[128];
  __shared__ float s_bn[8 * 128 * 2];               // [slot=row/2][col][sm|sq]

  bn_coef(step * 6 + l * 2, p.g1 + l * 128, p.b1 + l * 128, (float)(512 * n), s_scale, s_shift, tid);
  __syncthreads();
  {
    float4* sx4 = (float4*)s_x;
    for (int e4 = tid; e4 < 16 * 32; e4 += 256) {
      int row = e4 >> 5, d4 = e4 & 31;
      int r = r0 + row, b = r / n, i = r - b * n;
      float4 x = *(const float4*)(g_t + b * 2560 + i * 128 + d4 * 4);
      float4 sc = ((const float4*)s_scale)[d4];
      float4 sf = ((const float4*)s_shift)[d4];
      x.x = x.x * sc.x + sf.x; x.y = x.y * sc.y + sf.y;
      x.z = x.z * sc.z + sf.z; x.w = x.w * sc.w + sf.w;
      sx4[e4] = x;
    }
  }
  __syncthreads();
  // stage 1: hidden = relu(X @ W1 + fb1). cols cg*4..+3 (cg=g*64+lam), rows rh*8..+7.
  {
    const int cg = g * 64 + lam;
    float acc[8][4];
#pragma unroll
    for (int rr = 0; rr < 8; rr++)
#pragma unroll
      for (int c = 0; c < 4; c++) acc[rr][c] = 0.f;
    const float4* w1 = (const float4*)g_W1q + l * 16384 + cg;
    const float4* xx = (const float4*)s_x + rh * 8 * 32;
    float4 wb[4];
#pragma unroll
    for (int c = 0; c < 4; c++) wb[c] = w1[c * 128];
#pragma unroll 2
    for (int k4 = 0; k4 < 32; k4++) {
      float4 wn[4];
      const int kn = (k4 + 1) & 31;
#pragma unroll
      for (int c = 0; c < 4; c++) wn[c] = w1[kn * 512 + c * 128];
#pragma unroll
      for (int rr = 0; rr < 8; rr++) {
        float4 xr = xx[rr * 32 + k4];
#pragma unroll
        for (int c = 0; c < 4; c++) acc[rr][c] += DOT4(xr, wb[c]);
      }
#pragma unroll
      for (int c = 0; c < 4; c++) wb[c] = wn[c];
    }
    float4 b1v = *(const float4*)(p.fb1 + l * FFc + cg * 4);
#pragma unroll
    for (int rr = 0; rr < 8; rr++) {
      int row = rh * 8 + rr;
      float4 u;
      u.x = fmaxf(acc[rr][0] + b1v.x, 0.f); u.y = fmaxf(acc[rr][1] + b1v.y, 0.f);
      u.z = fmaxf(acc[rr][2] + b1v.z, 0.f); u.w = fmaxf(acc[rr][3] + b1v.w, 0.f);
      *(float4*)&s_hid[row * 512 + cg * 4] = u;
    }
  }
  __syncthreads();
  // stage 2: out = hid @ W2 + Xbn + fb2. col j=g*64+lam, rows rh*8..+7.
  {
    const int j = g * 64 + lam;
    float acc[8];
#pragma unroll
    for (int rr = 0; rr < 8; rr++) acc[rr] = 0.f;
    const float4* w2 = (const float4*)g_W2q + l * 16384 + j;
    const float4* hh = (const float4*)s_hid + rh * 8 * 128;
    float4 wb0 = w2[0], wb1 = w2[128];
#pragma unroll 2
    for (int k4 = 0; k4 < 128; k4++) {
      float4 wn = w2[((k4 + 2) & 127) * 128];
#pragma unroll
      for (int rr = 0; rr < 8; rr++) acc[rr] += DOT4(hh[rr * 128 + k4], wb0);
      wb0 = wb1; wb1 = wn;
    }
    const float f2 = p.fb2[l * 128 + j];
    float u[8];
#pragma unroll
    for (int rr = 0; rr < 8; rr++) {
      int row = rh * 8 + rr;
      int r = r0 + row, b = r / n, i = r - b * n;
      u[rr] = s_x[row * 128 + j] + acc[rr] + f2;
      g_t[b * 2560 + i * 128 + j] = u[rr];
    }
#pragma unroll
    for (int q = 0; q < 4; q++) {
      const int sb = ((rh * 4 + q) * 128 + j) * 2;
      s_bn[sb] = u[2 * q] + u[2 * q + 1];
      s_bn[sb + 1] = u[2 * q] * u[2 * q] + u[2 * q + 1] * u[2 * q + 1];
    }
  }
  __syncthreads();
  if (tid < 128) {
    float sm = 0.f, sq = 0.f;
#pragma unroll
    for (int rg = 0; rg < 8; rg++) { sm += s_bn[(rg * 128 + tid) * 2]; sq += s_bn[(rg * 128 + tid) * 2 + 1]; }
    float* slot = &g_bn[((step * 6 + l * 2 + 1) * 8 + (bx & 7)) * 256];
    atomicAdd(&slot[tid], sm);
    atomicAdd(&slot[128 + tid], sq);
  }
}

// KD (fused kd1+kd2): grid 512, 512 threads, one block per sample.
// W_node: thread = col (384 active), all n rows, static-unrolled stores.
__global__ __launch_bounds__(512, 4) void kd(Params p, int step) {
  const int tid = threadIdx.x, b = blockIdx.x;
  const int n = 20 - step;
  __shared__ __align__(16) float s_t[2560];
  __shared__ __align__(16) float s_dec[7680];
  __shared__ __align__(16) float s_scale[128], s_shift[128];
  __shared__ __align__(16) float s_gmean[128];
  __shared__ float s_red[512];
  __shared__ float s_qv[128], s_glq[128];
  __shared__ __align__(16) float s_gl[128];
  __shared__ float s_att[160];
  __shared__ float s_logits[20];
  __shared__ int s_sel;

  bn_coef(step * 6 + 5, p.g2 + 2 * 128, p.b2 + 2 * 128, (float)(512 * n), s_scale, s_shift, tid);
  __syncthreads();
  const float4* src4 = (const float4*)(g_t + b * 2560);
  float4* st4 = (float4*)s_t;
  for (int e4 = tid; e4 < n * 32; e4 += 512) {
    float4 x = src4[e4];
    float4 sc = ((const float4*)s_scale)[e4 & 31];
    float4 sf = ((const float4*)s_shift)[e4 & 31];
    x.x = x.x * sc.x + sf.x; x.y = x.y * sc.y + sf.y;
    x.z = x.z * sc.z + sf.z; x.w = x.w * sc.w + sf.w;
    st4[e4] = x;
  }
  __syncthreads();
  if (tid < 128) {
    float ssum = 0.f;
    for (int i2 = 0; i2 < n; i2++) ssum += s_t[i2 * 128 + tid];
    s_gmean[tid] = ssum / (float)n;
  }
  __syncthreads();
  // W_node -> s_dec. thread = col c (0..383), all n rows, static stores.
  if (tid < 384) {
    const int c = tid;
    const float4* w4 = (const float4*)g_Wnp + c;
    float acc[20];
#pragma unroll
    for (int i = 0; i < 20; i++) acc[i] = 0.f;
    float4 wb0 = w4[0], wb1 = w4[384];
#pragma unroll 2
    for (int d4 = 0; d4 < 32; d4++) {
      float4 wn = w4[((d4 + 2) & 31) * 384];
#pragma unroll
      for (int i = 0; i < 20; i++) {
        if (i < n) acc[i] += DOT4(st4[i * 32 + d4], wb0);
      }
      wb0 = wb1; wb1 = wn;
    }
#pragma unroll
    for (int i = 0; i < 20; i++) { if (i < n) s_dec[i * 384 + c] = acc[i]; }
  }
  // critic: jj = tid (all 512 cols in one pass)
  {
    const int jj = tid;
    float a = g_cctx[jj];
    const float4* wc4 = (const float4*)g_Wc1p + jj;
    const float4* gm4 = (const float4*)s_gmean;
    float4 wb0 = wc4[0], wb1 = wc4[512];
#pragma unroll 2
    for (int e4 = 0; e4 < 32; e4++) {
      float4 wn = wc4[((e4 + 2) & 31) * 512];
      float4 g = gm4[e4]; a += DOT4(g, wb0);
      wb0 = wb1; wb1 = wn;
    }
    s_red[tid] = fmaxf(a, 0.f) * p.Wc2[jj];
  }
  // query (tid<128) -> s_qv
  if (tid < 128) {
    float a = g_ctxq[tid];
    const float4* wf4 = (const float4*)g_Wfp + tid;
    const float4* gm4 = (const float4*)s_gmean;
    float4 wb0 = wf4[0], wb1 = wf4[128];
#pragma unroll 2
    for (int e4 = 0; e4 < 32; e4++) {
      float4 wn = wf4[((e4 + 2) & 31) * 128];
      float4 g = gm4[e4]; a += DOT4(g, wb0);
      wb0 = wb1; wb1 = wn;
    }
    s_qv[tid] = a;
  }
  __syncthreads();
#pragma unroll
  for (int sred = 256; sred > 0; sred >>= 1) {
    if (tid < sred) s_red[tid] += s_red[tid + sred];
    __syncthreads();
  }
  // glimpse attention
  for (int e = tid; e < Hc * n; e += 512) {
    int hh = e / n, m = e % n;
    float dacc = 0.f;
#pragma unroll
    for (int k2 = 0; k2 < 16; k2++) dacc += s_qv[hh * 16 + k2] * s_dec[m * 384 + hh * 16 + k2];
    s_att[hh * 20 + m] = dacc * 0.25f;
  }
  __syncthreads();
  if (tid < Hc) {
    float* row = s_att + tid * 20;
    float mx = row[0];
    for (int m = 1; m < n; m++) mx = fmaxf(mx, row[m]);
    float s = 0.f;
    for (int m = 0; m < n; m++) { float ev = __expf(row[m] - mx); row[m] = ev; s += ev; }
    float inv = 1.f / s;
    for (int m = 0; m < n; m++) row[m] *= inv;
  }
  __syncthreads();
  if (tid < 128) {
    int hh = tid >> 4;
    const float* arow = s_att + hh * 20;
    float acc = 0.f;
    for (int m = 0; m < n; m++) acc += arow[m] * s_dec[m * 384 + 128 + tid];
    s_gl[tid] = acc;
  }
  __syncthreads();
  if (tid < 128) {
    float a = 0.f;
    const float4* wo4 = (const float4*)g_Woup + tid;
    const float4* rr4 = (const float4*)s_gl;
    float4 wb0 = wo4[0], wb1 = wo4[128];
#pragma unroll 2
    for (int c4 = 0; c4 < 32; c4++) {
      float4 wn = wo4[((c4 + 2) & 31) * 128];
      float4 r = rr4[c4]; a += DOT4(r, wb0);
      wb0 = wb1; wb1 = wn;
    }
    s_glq[tid] = a;
  }
  __syncthreads();
  if (tid < n) {
    const float* lk = s_dec + tid * 384 + 256;
    float dacc = 0.f;
    for (int d = 0; d < 128; d++) dacc += s_glq[d] * lk[d];
    s_logits[tid] = 10.f * tanhf(dacc / 11.313708498984761f);
  }
  __syncthreads();
  if (tid == 0) {
    float mx = s_logits[0]; int sel = 0;
    for (int i2 = 1; i2 < n; i2++) if (s_logits[i2] > mx) { mx = s_logits[i2]; sel = i2; }
    float s = 0.f;
    for (int i2 = 0; i2 < n; i2++) s += __expf(s_logits[i2] - mx);
    p.out[b * 20 + step] = -logf(s);
    float cx = g_crd[b * 40 + 2 * sel], cy = g_crd[b * 40 + 2 * sel + 1];
    float ir = 0.f;
    if (step > 0) {
      float dx = cx - g_state[b * 8 + 0], dy = cy - g_state[b * 8 + 1];
      float dist = sqrtf(dx * dx + dy * dy);
      ir = -dist;
      g_state[b * 8 + 4] += dist;
    } else { g_state[b * 8 + 2] = cx; g_state[b * 8 + 3] = cy; g_state[b * 8 + 4] = 0.f; }
    p.out[10240 + b * 20 + step] = ir;
    p.out[31744 + b * 20 + step] = (float)g_idx[b * 20 + sel];
    g_state[b * 8 + 0] = cx; g_state[b * 8 + 1] = cy;
    if (step == 19) {
      float dx = g_state[b * 8 + 2] - cx, dy = g_state[b * 8 + 3] - cy;
      float dc = sqrtf(dx * dx + dy * dy);
      p.out[31232 + b] = -dc;
      p.out[30720 + b] = g_state[b * 8 + 4] + dc;
    }
    p.out[20480 + b * 20 + step] = s_red[0] + p.bc2[0];
    s_sel = sel;
  }
  __syncthreads();
  if (step < 19) {
    const int sel = s_sel;
    const int movecnt = (n - 1 - sel) * 128;
    float tmp[5]; float crdv = 0.f; int idxv = 0;
#pragma unroll
    for (int r = 0; r < 5; r++) { int e = tid + r * 512; if (e < movecnt) tmp[r] = g_x[b * 2560 + (sel + 1) * 128 + e]; }
    const int mc2 = (n - 1 - sel) * 2;
    if (tid < mc2) crdv = g_crd[b * 40 + (sel + 1) * 2 + tid];
    if (tid < n - 1 - sel) idxv = g_idx[b * 20 + sel + 1 + tid];
    __syncthreads();
#pragma unroll
    for (int r = 0; r < 5; r++) { int e = tid + r * 512; if (e < movecnt) g_x[b * 2560 + sel * 128 + e] = tmp[r]; }
    if (tid < mc2) g_crd[b * 40 + sel * 2 + tid] = crdv;
    if (tid < n - 1 - sel) g_idx[b * 20 + sel + tid] = idxv;
  }
}

extern "C" void kernel_launch(void* const* d_in, const int* in_sizes, int n_in,
                              void* d_out, int out_size, void* d_ws, size_t ws_size,
                              hipStream_t stream) {
  Params p;
  p.coords  = (const float*)d_in[0];
  p.Wi      = (const float*)d_in[1];
  p.bi      = (const float*)d_in[2];
  p.W_ph    = (const float*)d_in[3];
  p.Wq      = (const float*)d_in[4];
  p.Wk      = (const float*)d_in[5];
  p.Wv      = (const float*)d_in[6];
  p.Wo      = (const float*)d_in[7];
  p.g1      = (const float*)d_in[8];
  p.b1      = (const float*)d_in[9];
  p.fW1     = (const float*)d_in[10];
  p.fb1     = (const float*)d_in[11];
  p.fW2     = (const float*)d_in[12];
  p.fb2     = (const float*)d_in[13];
  p.g2      = (const float*)d_in[14];
  p.b2      = (const float*)d_in[15];
  p.W_node  = (const float*)d_in[16];
  p.W_fixed = (const float*)d_in[17];
  p.W_step  = (const float*)d_in[18];
  p.W_out   = (const float*)d_in[19];
  p.Wc1     = (const float*)d_in[20];
  p.bc1     = (const float*)d_in[21];
  p.Wc2     = (const float*)d_in[22];
  p.bc2     = (const float*)d_in[23];
  p.out = (float*)d_out;

  kinit<<<512, 256, 0, stream>>>(p);
  for (int step = 0; step < 20; step++) {
    const int n = 20 - step;
    for (int l = 0; l < 3; l++) {
      ka<<<512, 512, 0, stream>>>(p, step, l);
      kff<<<dim3(32 * n), 256, 0, stream>>>(p, step, l);
    }
    kd<<<512, 512, 0, stream>>>(p, step);
  }
}

// Round 13
// 5537.634 us; speedup vs baseline: 1.1495x; 1.1495x over previous
//
#include <hip/hip_runtime.h>
#include <cmath>

namespace {
constexpr int Hc = 8, FFc = 512, HIDc = 512;
}

struct Params {
  const float *coords, *Wi, *bi, *W_ph;
  const float *Wq, *Wk, *Wv, *Wo, *g1, *b1, *fW1, *fb1, *fW2, *fb2, *g2, *b2;
  const float *W_node, *W_fixed, *W_step, *W_out, *Wc1, *bc1, *Wc2, *bc2;
  float* out;
};

// Journal R25: R23/R24 confirmed ka/kd single-read maps are net-negative (ka
// pinned 75us both rounds; request lever only pays in kff). Revert ka/kd to
// R8 exact. R25 lever: the one BN-legal block-local fusion left — kd(step)
// + ka(step+1, l=0) share a launch (kda). kd's compaction writes sample b's
// g_x; ka(l=0) reads only sample b's g_x, no BN coefs => block-local dep,
// __syncthreads suffices. LDS phases overlaid (57.9KB <= ka's 58.9KB, same
// occupancy). Dispatches 141->122. All math/orders/slots identical.
__device__ __align__(16) float g_bn[120 * 8 * 256]; // BN stats, 8-way replicated
__device__ __align__(16) float g_x[512 * 2560];
__device__ __align__(16) float g_t[512 * 2560];
__device__ __align__(16) float g_crd[512 * 40];
__device__ int   g_idx[512 * 20];
__device__ float g_state[512 * 8];
__device__ __align__(16) float g_ctxq[128];
__device__ __align__(16) float g_cctx[512];
// Interleaved-packed weights: float4 at (k4*J + j) holds W[k4*4+0..3][j]
__device__ __align__(16) float g_Wqp[3 * 16384];    // [l][d4<32][j<128][4]
__device__ __align__(16) float g_Wkp[3 * 16384];
__device__ __align__(16) float g_Wvp[3 * 16384];
__device__ __align__(16) float g_Wop[3 * 16384];    // [l][c4<32][j<128][4]
// FF packs (wave-coherent column split):
__device__ __align__(16) float g_W1q[3 * 65536];    // [l][k4<32][c<4][cg<128][4]: col=cg*4+c
__device__ __align__(16) float g_W2q[3 * 65536];    // [l][k4<128][j<128][4]
__device__ __align__(16) float g_Wnp[49152];        // [e4<32][col<384][4]
__device__ __align__(16) float g_Wfp[16384];        // [e4<32][j<128][4]
__device__ __align__(16) float g_Woup[16384];       // [c4<32][j<128][4]
__device__ __align__(16) float g_Wc1p[65536];       // [e4<32][jj<512][4]

#define DOT4(a, b) ((a).x*(b).x + (a).y*(b).y + (a).z*(b).z + (a).w*(b).w)

__device__ __forceinline__ void bn_coef(int slot, const float* g, const float* bb, float cnt,
                                        float* s_scale, float* s_shift, int tid) {
  if (tid < 128) {
    float sm = 0.f, sq = 0.f;
#pragma unroll
    for (int r = 0; r < 8; r++) {
      const float* s = &g_bn[(slot * 8 + r) * 256];
      sm += s[tid]; sq += s[128 + tid];
    }
    float m_ = sm / cnt;
    float v_ = sq / cnt - m_ * m_;
    float rs = rsqrtf(v_ + 1e-5f);
    float sc = rs * g[tid];
    s_scale[tid] = sc;
    s_shift[tid] = bb[tid] - m_ * sc;
  }
}

__global__ __launch_bounds__(256) void kinit(Params p) {
  const int tid = threadIdx.x, b = blockIdx.x;
  const int gid = b * 256 + tid, GS = 512 * 256;
  for (int i = gid; i < 120 * 8 * 256; i += GS) g_bn[i] = 0.f;
  for (int e = tid; e < 2560; e += 256) {
    int i = e >> 7, d = e & 127;
    float cx = p.coords[b * 40 + 2 * i], cy = p.coords[b * 40 + 2 * i + 1];
    g_x[b * 2560 + e] = cx * p.Wi[d] + cy * p.Wi[128 + d] + p.bi[d];
  }
  if (tid < 40) g_crd[b * 40 + tid] = p.coords[b * 40 + tid];
  if (tid < 20) g_idx[b * 20 + tid] = tid;
  if (tid < 8) g_state[b * 8 + tid] = 0.f;
  if (b == 0) {
    if (tid < 128) {
      float a = 0.f;
      for (int j = 0; j < 256; j++) a += p.W_ph[j] * p.W_step[j * 128 + tid];
      g_ctxq[tid] = a;
    }
    for (int jj = tid; jj < 512; jj += 256) {
      float a = p.bc1[jj];
      for (int e = 0; e < 256; e++) a += p.W_ph[e] * p.Wc1[(128 + e) * 512 + jj];
      g_cctx[jj] = a;
    }
  }
  for (int e = gid; e < 3 * 16384; e += GS) {
    int sub = e & 3, rest = e >> 2;
    int j = rest & 127, rest2 = rest >> 7, d4 = rest2 & 31, l = rest2 >> 5;
    int d = d4 * 4 + sub;
    int src = l * 16384 + (j >> 4) * 2048 + d * 16 + (j & 15);
    g_Wqp[e] = p.Wq[src]; g_Wkp[e] = p.Wk[src]; g_Wvp[e] = p.Wv[src];
    int c = d;
    g_Wop[e] = p.Wo[l * 16384 + (c >> 4) * 2048 + (c & 15) * 128 + j];
  }
  // kff packs (wave-coherent layouts)
  for (int e = gid; e < 3 * 65536; e += GS) {
    int sub = e & 3, f = (e >> 2) & 16383, l = e >> 16;
    int cg = f & 127, c = (f >> 7) & 3, k4 = f >> 9;       // k4<32
    g_W1q[e] = p.fW1[l * 65536 + (k4 * 4 + sub) * 512 + cg * 4 + c];
  }
  for (int e = gid; e < 3 * 65536; e += GS) {
    int sub = e & 3, f = (e >> 2) & 16383, l = e >> 16;
    int j = f & 127, k4 = f >> 7;                          // k4<128
    g_W2q[e] = p.fW2[l * 65536 + (k4 * 4 + sub) * 128 + j];
  }
  for (int e = gid; e < 49152; e += GS) {
    int sub = e & 3, rest = e >> 2;
    int col = rest % 384, e4 = rest / 384;
    g_Wnp[e] = p.W_node[(e4 * 4 + sub) * 384 + col];
  }
  for (int e = gid; e < 16384; e += GS) {
    int sub = e & 3, rest = e >> 2;
    int j = rest & 127, e4 = rest >> 7;
    g_Wfp[e] = p.W_fixed[(e4 * 4 + sub) * 128 + j];
    g_Woup[e] = p.W_out[(e4 * 4 + sub) * 128 + j];
  }
  for (int e = gid; e < 65536; e += GS) {
    int sub = e & 3, rest = e >> 2;
    int jj = rest & 511, e4 = rest >> 9;
    g_Wc1p[e] = p.Wc1[(e4 * 4 + sub) * 512 + jj];
  }
}

// ---- shared device bodies (R8-exact math) ----

// ka body: [BN apply if l>0] -> QKV -> softmax -> AV -> out-proj -> g_t, BN1 stats.
// LDS: t(2560) q(2560) kT(2560) v(2560) att(3200) bnp(1024) scale/shift(256)
__device__ __forceinline__ void ka_body(const Params& p, int step, int l, int b, int tid,
                                        float* s_t, float* s_q, float* s_kT, float* s_v,
                                        float* s_att, float* s_bnp,
                                        float* s_scale, float* s_shift) {
  const int n = 20 - step;
  if (l > 0)
    bn_coef(step * 6 + (l - 1) * 2 + 1, p.g2 + (l - 1) * 128, p.b2 + (l - 1) * 128,
            (float)(512 * n), s_scale, s_shift, tid);
  __syncthreads();
  const float4* src4 = (const float4*)((l == 0 ? g_x : g_t) + b * 2560);
  float4* st4 = (float4*)s_t;
  for (int e4 = tid; e4 < n * 32; e4 += 512) {
    float4 x = src4[e4];
    if (l > 0) {
      float4 sc = ((const float4*)s_scale)[e4 & 31];
      float4 sh = ((const float4*)s_shift)[e4 & 31];
      x.x = x.x * sc.x + sh.x; x.y = x.y * sc.y + sh.y;
      x.z = x.z * sc.z + sh.z; x.w = x.w * sc.w + sh.w;
    }
    st4[e4] = x;
  }
  __syncthreads();
  // QKV: j = tid&127 (all heads), rows rg2 + 4r (rg2 = tid>>7 < 4, r < 5).
  {
    const int j = tid & 127, rg2 = tid >> 7;
    const float4* wq4 = (const float4*)g_Wqp + l * 4096 + j;
    const float4* wk4 = (const float4*)g_Wkp + l * 4096 + j;
    const float4* wv4 = (const float4*)g_Wvp + l * 4096 + j;
    float aq[5], ak[5], av[5];
#pragma unroll
    for (int r = 0; r < 5; r++) { aq[r] = 0.f; ak[r] = 0.f; av[r] = 0.f; }
    float4 bq = wq4[0], bk = wk4[0], bv = wv4[0];
#pragma unroll 2
    for (int d4 = 0; d4 < 32; d4++) {
      const int dn = (d4 + 1) & 31;
      float4 nq = wq4[dn * 128], nk = wk4[dn * 128], nv = wv4[dn * 128];
#pragma unroll
      for (int r = 0; r < 5; r++) {
        int i = rg2 + 4 * r;
        if (i < n) {
          float4 x = st4[i * 32 + d4];
          aq[r] += DOT4(x, bq); ak[r] += DOT4(x, bk); av[r] += DOT4(x, bv);
        }
      }
      bq = nq; bk = nk; bv = nv;
    }
#pragma unroll
    for (int r = 0; r < 5; r++) {
      int i = rg2 + 4 * r;
      if (i < n) {
        s_q[i * 128 + j] = aq[r];
        s_kT[j * 20 + i] = ak[r];
        s_v[i * 128 + j] = av[r];
      }
    }
  }
  __syncthreads();
  const int nn = n * n;
  for (int e = tid; e < 8 * nn; e += 512) {
    int hl = e / nn, rem = e % nn, i = rem / n, m = rem % n;
    float dacc = 0.f;
#pragma unroll
    for (int k2 = 0; k2 < 16; k2++)
      dacc += s_q[i * 128 + hl * 16 + k2] * s_kT[(hl * 16 + k2) * 20 + m];
    s_att[hl * 400 + i * 20 + m] = dacc * 0.25f;
  }
  __syncthreads();
  for (int r = tid; r < 8 * n; r += 512) {
    int hl = r / n, i = r % n;
    float* row = s_att + hl * 400 + i * 20;
    float mx = row[0];
    for (int m = 1; m < n; m++) mx = fmaxf(mx, row[m]);
    float s = 0.f;
    for (int m = 0; m < n; m++) { float ev = __expf(row[m] - mx); row[m] = ev; s += ev; }
    float inv = 1.f / s;
    for (int m = 0; m < n; m++) row[m] *= inv;
  }
  __syncthreads();
  // AV -> s_q (s_q free after QK^T)
  for (int e = tid; e < 8 * n * 16; e += 512) {
    int hl = e / (n * 16), rem = e % (n * 16), i = rem >> 4, k2 = rem & 15;
    const float* arow = s_att + hl * 400 + i * 20;
    float acc = 0.f;
    for (int m = 0; m < n; m++) acc += arow[m] * s_v[m * 128 + hl * 16 + k2];
    s_q[i * 128 + hl * 16 + k2] = acc;
  }
  __syncthreads();
  // out-proj + residual -> g_t, BN1 partials. ka2's exact thread->row map.
  {
    const int j2 = tid & 127, rh2 = tid >> 7;
    const int s = rh2 & 1, rhalf = rh2 >> 1;
    const float4* sh4 = (const float4*)s_q;
    float acc[5];
#pragma unroll
    for (int r = 0; r < 5; r++) {
      int i = s + 2 * (rhalf + 2 * r);
      acc[r] = (i < n) ? s_t[i * 128 + j2] : 0.f;
    }
    const float4* wo4 = (const float4*)g_Wop + l * 4096 + j2;
    float4 wb0 = wo4[0], wb1 = wo4[128];
#pragma unroll 2
    for (int c4 = 0; c4 < 32; c4++) {
      float4 wn = wo4[((c4 + 2) & 31) * 128];
#pragma unroll
      for (int r = 0; r < 5; r++) {
        int i = s + 2 * (rhalf + 2 * r);
        if (i < n) { float4 h = sh4[i * 32 + c4]; acc[r] += DOT4(h, wb0); }
      }
      wb0 = wb1; wb1 = wn;
    }
    float sm = 0.f, sq = 0.f;
#pragma unroll
    for (int r = 0; r < 5; r++) {
      int i = s + 2 * (rhalf + 2 * r);
      if (i < n) { g_t[b * 2560 + i * 128 + j2] = acc[r]; sm += acc[r]; sq += acc[r] * acc[r]; }
    }
    s_bnp[(rh2 * 128 + j2) * 2] = sm;
    s_bnp[(rh2 * 128 + j2) * 2 + 1] = sq;
  }
  __syncthreads();
  if (tid < 128) {
    float sm = 0.f, sq = 0.f;
#pragma unroll
    for (int h = 0; h < 4; h++) { sm += s_bnp[(h * 128 + tid) * 2]; sq += s_bnp[(h * 128 + tid) * 2 + 1]; }
    float* slot = &g_bn[((step * 6 + l * 2) * 8 + (b & 7)) * 256];
    atomicAdd(&slot[tid], sm);
    atomicAdd(&slot[128 + tid], sq);
  }
}

// kd body (R8-exact): BN2(l=2) apply -> W_node -> gmean -> critic -> query ->
// glimpse -> logits -> outputs -> compaction.
__device__ __forceinline__ void kd_body(const Params& p, int step, int b, int tid,
                                        float* s_t, float* s_dec, float* s_gmean,
                                        float* s_red, float* s_qv, float* s_glq,
                                        float* s_gl, float* s_att, float* s_logits,
                                        float* s_scale, float* s_shift, int* s_sel) {
  const int n = 20 - step;
  bn_coef(step * 6 + 5, p.g2 + 2 * 128, p.b2 + 2 * 128, (float)(512 * n), s_scale, s_shift, tid);
  __syncthreads();
  const float4* src4 = (const float4*)(g_t + b * 2560);
  float4* st4 = (float4*)s_t;
  for (int e4 = tid; e4 < n * 32; e4 += 512) {
    float4 x = src4[e4];
    float4 sc = ((const float4*)s_scale)[e4 & 31];
    float4 sf = ((const float4*)s_shift)[e4 & 31];
    x.x = x.x * sc.x + sf.x; x.y = x.y * sc.y + sf.y;
    x.z = x.z * sc.z + sf.z; x.w = x.w * sc.w + sf.w;
    st4[e4] = x;
  }
  __syncthreads();
  if (tid < 128) {
    float ssum = 0.f;
    for (int i2 = 0; i2 < n; i2++) ssum += s_t[i2 * 128 + tid];
    s_gmean[tid] = ssum / (float)n;
  }
  __syncthreads();
  // W_node: all 384 cols -> s_dec. cb=tid&63, rg=tid>>6 (8 groups, rows rg+8r).
  {
    const int cb = tid & 63, rg = tid >> 6;
    float acc[6][3];
#pragma unroll
    for (int cc = 0; cc < 6; cc++)
#pragma unroll
      for (int r = 0; r < 3; r++) acc[cc][r] = 0.f;
    const float4* wn4 = (const float4*)g_Wnp + cb;
    float4 wb[6];
#pragma unroll
    for (int cc = 0; cc < 6; cc++) wb[cc] = wn4[cc * 64];
#pragma unroll 2
    for (int d4 = 0; d4 < 32; d4++) {
      const int dn = (d4 + 1) & 31;
      float4 wn[6];
#pragma unroll
      for (int cc = 0; cc < 6; cc++) wn[cc] = wn4[dn * 384 + cc * 64];
#pragma unroll
      for (int r = 0; r < 3; r++) {
        int i = rg + 8 * r;
        if (i < n) {
          float4 x = st4[i * 32 + d4];
#pragma unroll
          for (int cc = 0; cc < 6; cc++) acc[cc][r] += DOT4(x, wb[cc]);
        }
      }
#pragma unroll
      for (int cc = 0; cc < 6; cc++) wb[cc] = wn[cc];
    }
#pragma unroll
    for (int r = 0; r < 3; r++) {
      int i = rg + 8 * r;
      if (i < n) {
#pragma unroll
        for (int cc = 0; cc < 6; cc++)
          s_dec[i * 384 + cb + 64 * cc] = acc[cc][r];
      }
    }
  }
  // critic: jj = tid (all 512 cols in one pass)
  {
    const int jj = tid;
    float a = g_cctx[jj];
    const float4* wc4 = (const float4*)g_Wc1p + jj;
    const float4* gm4 = (const float4*)s_gmean;
    float4 wb0 = wc4[0], wb1 = wc4[512];
#pragma unroll 2
    for (int e4 = 0; e4 < 32; e4++) {
      float4 wn = wc4[((e4 + 2) & 31) * 512];
      float4 g = gm4[e4]; a += DOT4(g, wb0);
      wb0 = wb1; wb1 = wn;
    }
    s_red[tid] = fmaxf(a, 0.f) * p.Wc2[jj];
  }
  // query (tid<128) -> s_qv
  if (tid < 128) {
    float a = g_ctxq[tid];
    const float4* wf4 = (const float4*)g_Wfp + tid;
    const float4* gm4 = (const float4*)s_gmean;
    float4 wb0 = wf4[0], wb1 = wf4[128];
#pragma unroll 2
    for (int e4 = 0; e4 < 32; e4++) {
      float4 wn = wf4[((e4 + 2) & 31) * 128];
      float4 g = gm4[e4]; a += DOT4(g, wb0);
      wb0 = wb1; wb1 = wn;
    }
    s_qv[tid] = a;
  }
  __syncthreads();
#pragma unroll
  for (int sred = 256; sred > 0; sred >>= 1) {
    if (tid < sred) s_red[tid] += s_red[tid + sred];
    __syncthreads();
  }
  // glimpse attention
  for (int e = tid; e < Hc * n; e += 512) {
    int hh = e / n, m = e % n;
    float dacc = 0.f;
#pragma unroll
    for (int k2 = 0; k2 < 16; k2++) dacc += s_qv[hh * 16 + k2] * s_dec[m * 384 + hh * 16 + k2];
    s_att[hh * 20 + m] = dacc * 0.25f;
  }
  __syncthreads();
  if (tid < Hc) {
    float* row = s_att + tid * 20;
    float mx = row[0];
    for (int m = 1; m < n; m++) mx = fmaxf(mx, row[m]);
    float s = 0.f;
    for (int m = 0; m < n; m++) { float ev = __expf(row[m] - mx); row[m] = ev; s += ev; }
    float inv = 1.f / s;
    for (int m = 0; m < n; m++) row[m] *= inv;
  }
  __syncthreads();
  if (tid < 128) {
    int hh = tid >> 4;
    const float* arow = s_att + hh * 20;
    float acc = 0.f;
    for (int m = 0; m < n; m++) acc += arow[m] * s_dec[m * 384 + 128 + tid];
    s_gl[tid] = acc;
  }
  __syncthreads();
  if (tid < 128) {
    float a = 0.f;
    const float4* wo4 = (const float4*)g_Woup + tid;
    const float4* rr4 = (const float4*)s_gl;
    float4 wb0 = wo4[0], wb1 = wo4[128];
#pragma unroll 2
    for (int c4 = 0; c4 < 32; c4++) {
      float4 wn = wo4[((c4 + 2) & 31) * 128];
      float4 r = rr4[c4]; a += DOT4(r, wb0);
      wb0 = wb1; wb1 = wn;
    }
    s_glq[tid] = a;
  }
  __syncthreads();
  if (tid < n) {
    const float* lk = s_dec + tid * 384 + 256;
    float dacc = 0.f;
    for (int d = 0; d < 128; d++) dacc += s_glq[d] * lk[d];
    s_logits[tid] = 10.f * tanhf(dacc / 11.313708498984761f);
  }
  __syncthreads();
  if (tid == 0) {
    float mx = s_logits[0]; int sel = 0;
    for (int i2 = 1; i2 < n; i2++) if (s_logits[i2] > mx) { mx = s_logits[i2]; sel = i2; }
    float s = 0.f;
    for (int i2 = 0; i2 < n; i2++) s += __expf(s_logits[i2] - mx);
    p.out[b * 20 + step] = -logf(s);
    float cx = g_crd[b * 40 + 2 * sel], cy = g_crd[b * 40 + 2 * sel + 1];
    float ir = 0.f;
    if (step > 0) {
      float dx = cx - g_state[b * 8 + 0], dy = cy - g_state[b * 8 + 1];
      float dist = sqrtf(dx * dx + dy * dy);
      ir = -dist;
      g_state[b * 8 + 4] += dist;
    } else { g_state[b * 8 + 2] = cx; g_state[b * 8 + 3] = cy; g_state[b * 8 + 4] = 0.f; }
    p.out[10240 + b * 20 + step] = ir;
    p.out[31744 + b * 20 + step] = (float)g_idx[b * 20 + sel];
    g_state[b * 8 + 0] = cx; g_state[b * 8 + 1] = cy;
    if (step == 19) {
      float dx = g_state[b * 8 + 2] - cx, dy = g_state[b * 8 + 3] - cy;
      float dc = sqrtf(dx * dx + dy * dy);
      p.out[31232 + b] = -dc;
      p.out[30720 + b] = g_state[b * 8 + 4] + dc;
    }
    p.out[20480 + b * 20 + step] = s_red[0] + p.bc2[0];
    *s_sel = sel;
  }
  __syncthreads();
  if (step < 19) {
    const int sel = *s_sel;
    const int movecnt = (n - 1 - sel) * 128;
    float tmp[5]; float crdv = 0.f; int idxv = 0;
#pragma unroll
    for (int r = 0; r < 5; r++) { int e = tid + r * 512; if (e < movecnt) tmp[r] = g_x[b * 2560 + (sel + 1) * 128 + e]; }
    const int mc2 = (n - 1 - sel) * 2;
    if (tid < mc2) crdv = g_crd[b * 40 + (sel + 1) * 2 + tid];
    if (tid < n - 1 - sel) idxv = g_idx[b * 20 + sel + 1 + tid];
    __syncthreads();
#pragma unroll
    for (int r = 0; r < 5; r++) { int e = tid + r * 512; if (e < movecnt) g_x[b * 2560 + sel * 128 + e] = tmp[r]; }
    if (tid < mc2) g_crd[b * 40 + sel * 2 + tid] = crdv;
    if (tid < n - 1 - sel) g_idx[b * 20 + sel + tid] = idxv;
  }
}

// ---- kernels ----

// KA standalone: used for (step=0,l=0) and all l=1,2.
__global__ __launch_bounds__(512, 4) void ka(Params p, int step, int l) {
  const int tid = threadIdx.x, b = blockIdx.x;
  __shared__ __align__(16) float smem[14464];
  ka_body(p, step, l, b, tid,
          smem, smem + 2560, smem + 5120, smem + 7680,
          smem + 10240, smem + 13440, smem + 13440 + 512, smem + 13440 + 640);
}
// NOTE: ka scale/shift share the tail of smem after s_bnp(1024): offsets
// 13440+512? -> see layout check below (bnp needs 1024; scale/shift 256 more).

// KDA: kd(step) then ka(step+1, l=0) in one launch (block-local dependency).
__global__ __launch_bounds__(512, 4) void kda(Params p, int step) {
  const int tid = threadIdx.x, b = blockIdx.x;
  __shared__ __align__(16) float smem[14464];
  __shared__ int s_sel;
  // kd phase layout
  kd_body(p, step, b, tid,
          smem,                 // s_t 2560
          smem + 2560,          // s_dec 7680
          smem + 10240,         // s_gmean 128
          smem + 10368,         // s_red 512
          smem + 10880,         // s_qv 128
          smem + 11008,         // s_glq 128
          smem + 11136,         // s_gl 128
          smem + 11264,         // s_att 160
          smem + 11424,         // s_logits 32(20)
          smem + 11456,         // s_scale 128
          smem + 11584,         // s_shift 128
          &s_sel);
  __syncthreads();              // compaction done; smem free; g_x visible in-block
  // ka(step+1, l=0) phase (no BN coefs needed for l=0)
  ka_body(p, step + 1, 0, b, tid,
          smem, smem + 2560, smem + 5120, smem + 7680,
          smem + 10240, smem + 13440, smem + 13440 + 512, smem + 13440 + 640);
}

// KD standalone: only for step 19.
__global__ __launch_bounds__(512, 4) void kd(Params p, int step) {
  const int tid = threadIdx.x, b = blockIdx.x;
  __shared__ __align__(16) float smem[11712];
  __shared__ int s_sel;
  kd_body(p, step, b, tid,
          smem, smem + 2560, smem + 10240, smem + 10368, smem + 10880,
          smem + 11008, smem + 11136, smem + 11264, smem + 11424,
          smem + 11456, smem + 11584, &s_sel);
}

// KFF: R19 exact (best measured). grid 32n blocks of 16 rows, 256 threads,
// 2 col-groups x 2 row-waves of 8 rows.
__global__ __launch_bounds__(256, 4) void kff(Params p, int step, int l) {
  const int tid = threadIdx.x, bx = blockIdx.x;
  const int n = 20 - step;
  const int r0 = bx * 16;
  const int wid = tid >> 6, lam = tid & 63;
  const int g = wid >> 1, rh = wid & 1;
  __shared__ __align__(16) float s_x[16 * 128];     // BN1-applied X tile
  __shared__ __align__(16) float s_hid[16 * 512];   // hidden
  __shared__ __align__(16) float s_scale[128], s_shift[128];
  __shared__ float s_bn[8 * 128 * 2];               // [slot=row/2][col][sm|sq]

  bn_coef(step * 6 + l * 2, p.g1 + l * 128, p.b1 + l * 128, (float)(512 * n), s_scale, s_shift, tid);
  __syncthreads();
  {
    float4* sx4 = (float4*)s_x;
    for (int e4 = tid; e4 < 16 * 32; e4 += 256) {
      int row = e4 >> 5, d4 = e4 & 31;
      int r = r0 + row, b = r / n, i = r - b * n;
      float4 x = *(const float4*)(g_t + b * 2560 + i * 128 + d4 * 4);
      float4 sc = ((const float4*)s_scale)[d4];
      float4 sf = ((const float4*)s_shift)[d4];
      x.x = x.x * sc.x + sf.x; x.y = x.y * sc.y + sf.y;
      x.z = x.z * sc.z + sf.z; x.w = x.w * sc.w + sf.w;
      sx4[e4] = x;
    }
  }
  __syncthreads();
  // stage 1: hidden = relu(X @ W1 + fb1). cols cg*4..+3 (cg=g*64+lam), rows rh*8..+7.
  {
    const int cg = g * 64 + lam;
    float acc[8][4];
#pragma unroll
    for (int rr = 0; rr < 8; rr++)
#pragma unroll
      for (int c = 0; c < 4; c++) acc[rr][c] = 0.f;
    const float4* w1 = (const float4*)g_W1q + l * 16384 + cg;
    const float4* xx = (const float4*)s_x + rh * 8 * 32;
    float4 wb[4];
#pragma unroll
    for (int c = 0; c < 4; c++) wb[c] = w1[c * 128];
#pragma unroll 2
    for (int k4 = 0; k4 < 32; k4++) {
      float4 wn[4];
      const int kn = (k4 + 1) & 31;
#pragma unroll
      for (int c = 0; c < 4; c++) wn[c] = w1[kn * 512 + c * 128];
#pragma unroll
      for (int rr = 0; rr < 8; rr++) {
        float4 xr = xx[rr * 32 + k4];
#pragma unroll
        for (int c = 0; c < 4; c++) acc[rr][c] += DOT4(xr, wb[c]);
      }
#pragma unroll
      for (int c = 0; c < 4; c++) wb[c] = wn[c];
    }
    float4 b1v = *(const float4*)(p.fb1 + l * FFc + cg * 4);
#pragma unroll
    for (int rr = 0; rr < 8; rr++) {
      int row = rh * 8 + rr;
      float4 u;
      u.x = fmaxf(acc[rr][0] + b1v.x, 0.f); u.y = fmaxf(acc[rr][1] + b1v.y, 0.f);
      u.z = fmaxf(acc[rr][2] + b1v.z, 0.f); u.w = fmaxf(acc[rr][3] + b1v.w, 0.f);
      *(float4*)&s_hid[row * 512 + cg * 4] = u;
    }
  }
  __syncthreads();
  // stage 2: out = hid @ W2 + Xbn + fb2. col j=g*64+lam, rows rh*8..+7.
  {
    const int j = g * 64 + lam;
    float acc[8];
#pragma unroll
    for (int rr = 0; rr < 8; rr++) acc[rr] = 0.f;
    const float4* w2 = (const float4*)g_W2q + l * 16384 + j;
    const float4* hh = (const float4*)s_hid + rh * 8 * 128;
    float4 wb0 = w2[0], wb1 = w2[128];
#pragma unroll 2
    for (int k4 = 0; k4 < 128; k4++) {
      float4 wn = w2[((k4 + 2) & 127) * 128];
#pragma unroll
      for (int rr = 0; rr < 8; rr++) acc[rr] += DOT4(hh[rr * 128 + k4], wb0);
      wb0 = wb1; wb1 = wn;
    }
    const float f2 = p.fb2[l * 128 + j];
    float u[8];
#pragma unroll
    for (int rr = 0; rr < 8; rr++) {
      int row = rh * 8 + rr;
      int r = r0 + row, b = r / n, i = r - b * n;
      u[rr] = s_x[row * 128 + j] + acc[rr] + f2;
      g_t[b * 2560 + i * 128 + j] = u[rr];
    }
#pragma unroll
    for (int q = 0; q < 4; q++) {
      const int sb = ((rh * 4 + q) * 128 + j) * 2;
      s_bn[sb] = u[2 * q] + u[2 * q + 1];
      s_bn[sb + 1] = u[2 * q] * u[2 * q] + u[2 * q + 1] * u[2 * q + 1];
    }
  }
  __syncthreads();
  if (tid < 128) {
    float sm = 0.f, sq = 0.f;
#pragma unroll
    for (int rg = 0; rg < 8; rg++) { sm += s_bn[(rg * 128 + tid) * 2]; sq += s_bn[(rg * 128 + tid) * 2 + 1]; }
    float* slot = &g_bn[((step * 6 + l * 2 + 1) * 8 + (bx & 7)) * 256];
    atomicAdd(&slot[tid], sm);
    atomicAdd(&slot[128 + tid], sq);
  }
}

extern "C" void kernel_launch(void* const* d_in, const int* in_sizes, int n_in,
                              void* d_out, int out_size, void* d_ws, size_t ws_size,
                              hipStream_t stream) {
  Params p;
  p.coords  = (const float*)d_in[0];
  p.Wi      = (const float*)d_in[1];
  p.bi      = (const float*)d_in[2];
  p.W_ph    = (const float*)d_in[3];
  p.Wq      = (const float*)d_in[4];
  p.Wk      = (const float*)d_in[5];
  p.Wv      = (const float*)d_in[6];
  p.Wo      = (const float*)d_in[7];
  p.g1      = (const float*)d_in[8];
  p.b1      = (const float*)d_in[9];
  p.fW1     = (const float*)d_in[10];
  p.fb1     = (const float*)d_in[11];
  p.fW2     = (const float*)d_in[12];
  p.fb2     = (const float*)d_in[13];
  p.g2      = (const float*)d_in[14];
  p.b2      = (const float*)d_in[15];
  p.W_node  = (const float*)d_in[16];
  p.W_fixed = (const float*)d_in[17];
  p.W_step  = (const float*)d_in[18];
  p.W_out   = (const float*)d_in[19];
  p.Wc1     = (const float*)d_in[20];
  p.bc1     = (const float*)d_in[21];
  p.Wc2     = (const float*)d_in[22];
  p.bc2     = (const float*)d_in[23];
  p.out = (float*)d_out;

  kinit<<<512, 256, 0, stream>>>(p);
  for (int step = 0; step < 20; step++) {
    const int n = 20 - step;
    for (int l = 0; l < 3; l++) {
      if (!(l == 0 && step > 0))           // ka(step,0) for step>0 ran inside kda(step-1)
        ka<<<512, 512, 0, stream>>>(p, step, l);
      kff<<<dim3(32 * n), 256, 0, stream>>>(p, step, l);
    }
    if (step < 19) kda<<<512, 512, 0, stream>>>(p, step);
    else           kd<<<512, 512, 0, stream>>>(p, step);
  }
}